// Round 12
// baseline (556.829 us; speedup 1.0000x reference)
//
#include <hip/hip_runtime.h>
#include <math.h>

typedef __bf16 bf16_t;
typedef __bf16 bf16x8 __attribute__((ext_vector_type(8)));
typedef float f32x4 __attribute__((ext_vector_type(4)));

#define NN 8192
#define L2E 1.44269504088896340736f
#define SMAX 45.0f                    // fixed softmax shift: s-SMAX in [-75,+15], all normal fp32
#define KSCALE 0.35355339059327373f   // 1/sqrt(8); applied to khs on both sides => kh·kh/8

// ---------------------------------------------------------------------------
// Kernel 1: projections (verified R5-R10).
// ---------------------------------------------------------------------------
__global__ __launch_bounds__(256) void proj_kernel(
    const float* __restrict__ input,
    const float* __restrict__ kW,
    const float* __restrict__ vW,
    bf16_t* __restrict__ khs_hi,
    bf16_t* __restrict__ khs_lo,
    bf16_t* __restrict__ vhT)
{
    __shared__ __align__(16) bf16_t WkH[64][136];
    __shared__ __align__(16) bf16_t WkL[64][136];
    __shared__ __align__(16) bf16_t WvH[64][136];
    __shared__ __align__(16) bf16_t WvL[64][136];

    const int tid   = threadIdx.x;
    const int wv    = tid >> 6;
    const int lane  = tid & 63;
    const int l15   = lane & 15;
    const int quad  = lane >> 4;
    const int rbase = blockIdx.x * 64 + wv * 16;

    f32x4 kacc[4] = {};
    f32x4 vacc[4] = {};

    for (int kk = 0; kk < 4; ++kk) {
        __syncthreads();
        #pragma unroll
        for (int i = 0; i < 32; ++i) {
            int idx = tid + i * 256;
            int kl  = idx >> 6;
            int n   = idx & 63;
            float wk  = kW[(kk * 128 + kl) * 64 + n];
            float wv2 = vW[(kk * 128 + kl) * 64 + n];
            bf16_t kh = (bf16_t)wk;
            bf16_t vh = (bf16_t)wv2;
            WkH[n][kl] = kh;  WkL[n][kl] = (bf16_t)(wk - (float)kh);
            WvH[n][kl] = vh;  WvL[n][kl] = (bf16_t)(wv2 - (float)vh);
        }
        __syncthreads();

        #pragma unroll
        for (int kc = 0; kc < 4; ++kc) {
            const float* ap = &input[(size_t)(rbase + l15) * 512 + kk * 128 + kc * 32 + quad * 8];
            f32x4 a0 = *(const f32x4*)ap;
            f32x4 a1 = *(const f32x4*)(ap + 4);
            bf16x8 ah, al;
            #pragma unroll
            for (int j = 0; j < 4; ++j) {
                bf16_t h0 = (bf16_t)a0[j], h1 = (bf16_t)a1[j];
                ah[j]     = h0;  al[j]     = (bf16_t)(a0[j] - (float)h0);
                ah[4 + j] = h1;  al[4 + j] = (bf16_t)(a1[j] - (float)h1);
            }
            #pragma unroll
            for (int nb = 0; nb < 4; ++nb) {
                bf16x8 bkh = *(const bf16x8*)&WkH[nb * 16 + l15][kc * 32 + quad * 8];
                bf16x8 bkl = *(const bf16x8*)&WkL[nb * 16 + l15][kc * 32 + quad * 8];
                bf16x8 bvh = *(const bf16x8*)&WvH[nb * 16 + l15][kc * 32 + quad * 8];
                bf16x8 bvl = *(const bf16x8*)&WvL[nb * 16 + l15][kc * 32 + quad * 8];
                kacc[nb] = __builtin_amdgcn_mfma_f32_16x16x32_bf16(ah, bkh, kacc[nb], 0, 0, 0);
                kacc[nb] = __builtin_amdgcn_mfma_f32_16x16x32_bf16(al, bkh, kacc[nb], 0, 0, 0);
                kacc[nb] = __builtin_amdgcn_mfma_f32_16x16x32_bf16(ah, bkl, kacc[nb], 0, 0, 0);
                vacc[nb] = __builtin_amdgcn_mfma_f32_16x16x32_bf16(ah, bvh, vacc[nb], 0, 0, 0);
                vacc[nb] = __builtin_amdgcn_mfma_f32_16x16x32_bf16(al, bvh, vacc[nb], 0, 0, 0);
                vacc[nb] = __builtin_amdgcn_mfma_f32_16x16x32_bf16(ah, bvl, vacc[nb], 0, 0, 0);
            }
        }
    }

    #pragma unroll
    for (int nb = 0; nb < 4; ++nb) {
        const int dcol = nb * 16 + l15;
        #pragma unroll
        for (int r = 0; r < 4; ++r) {
            float v  = kacc[nb][r] * KSCALE;
            bf16_t h = (bf16_t)v;
            khs_hi[(size_t)(rbase + quad * 4 + r) * 64 + dcol] = h;
            khs_lo[(size_t)(rbase + quad * 4 + r) * 64 + dcol] = (bf16_t)(v - (float)h);
        }
        union { bf16_t b[4]; uint2 u; } pk;
        #pragma unroll
        for (int r = 0; r < 4; ++r) pk.b[r] = (bf16_t)vacc[nb][r];
        *(uint2*)&vhT[(size_t)dcol * NN + rbase + quad * 4] = pk.u;
    }
}

// ---------------------------------------------------------------------------
// Kernel 1c: repack K/V into MFMA-fragment-tiled layout (verified R10).
// ---------------------------------------------------------------------------
__global__ __launch_bounds__(256) void repack(
    const bf16_t* __restrict__ khs_hi, const bf16_t* __restrict__ vhT,
    bf16_t* __restrict__ ktile, bf16_t* __restrict__ vtile)
{
    int idx = blockIdx.x * 256 + threadIdx.x;       // 0..131071
    int c    = idx & 65535;
    int t    = c >> 8;
    int rem  = c & 255;
    int f    = rem >> 6;
    int lane = rem & 63;
    int quad = lane >> 4;
    int l15  = lane & 15;
    if (idx < 65536) {
        int kperm = ((l15 >> 2) << 3) | (l15 & 3);
        int key = 32 * t + kperm + (f >> 1) * 4;
        int dim = (f & 1) * 32 + quad * 8;
        uint4 v = *(const uint4*)(khs_hi + (size_t)key * 64 + dim);
        *(uint4*)(ktile + (size_t)t * 2048 + f * 512 + lane * 8) = v;
    } else {
        uint4 v = *(const uint4*)(vhT + (size_t)(16 * f + l15) * NN + 32 * t + quad * 8);
        *(uint4*)(vtile + (size_t)t * 2048 + f * 512 + lane * 8) = v;
    }
}

// ---------------------------------------------------------------------------
// Kernel 2: fused mask-pack + fixed-max attention + merge + ELU + store.
// 512 blocks x 512 threads; block owns 16 q-rows END-TO-END (no atomics).
// Mask LDS layout (R11 bugfix): CHUNKED — chunk c = word>>5 (c==wave that
// reads it), within chunk: [row][word&31] with 34-dword row stride.
//   write: ShBuf[(g>>4)*544 + row*34 + ((2g)&31)]  (b64, lane 0)
//   read : ShBuf[w*544 + l15*34 + t]               (b32, conflict-free:
//          bank = (2*l15 + t) % 32, quads broadcast)
// Main loop math identical to R10. Epilogue: 8-wave sum-tree, ELU, store.
// ---------------------------------------------------------------------------
__global__ __launch_bounds__(512, 4) void attn_kernel(
    const int* __restrict__ adj,             // [8192][8192]
    const bf16_t* __restrict__ khs_hi,
    const bf16_t* __restrict__ khs_lo,
    const bf16_t* __restrict__ ktile,        // [256 tiles][4][512] bf16
    const bf16_t* __restrict__ vtile,        // [256 tiles][4][512] bf16
    float* __restrict__ out)                 // [8192][64] fp32
{
    // overlay: phase1 = chunked mask words (8*544 dwords); phase3 = merge slabs
    __shared__ __align__(16) unsigned int ShBuf[8 * 544];   // 17.4 KB

    const int tid   = threadIdx.x;
    const int w     = tid >> 6;
    const int lane  = tid & 63;
    const int l15   = lane & 15;
    const int quad  = lane >> 4;
    const int qbase = blockIdx.x * 16;

    // ---- phase 1: pack this block's adj rows into LDS (ballot) ----
    {
        #pragma unroll 2
        for (int r2 = 0; r2 < 2; ++r2) {
            const int row = 2 * w + r2;                         // 0..15
            const int* rp = adj + (size_t)(qbase + row) * NN + lane;
            #pragma unroll 8
            for (int g = 0; g < 128; ++g) {
                int v = rp[g * 64];
                unsigned long long b = __ballot(v > 0);         // bit i = col g*64+i
                if (lane == 0)
                    *(unsigned long long*)&ShBuf[(g >> 4) * 544 + row * 34 + ((2 * g) & 31)] = b;
            }
        }
    }
    __syncthreads();

    // ---- phase 2: main loop ----
    const bf16x8 qh0 = *(const bf16x8*)&khs_hi[(size_t)(qbase + l15) * 64 + quad * 8];
    const bf16x8 qh1 = *(const bf16x8*)&khs_hi[(size_t)(qbase + l15) * 64 + 32 + quad * 8];
    const bf16x8 ql0 = *(const bf16x8*)&khs_lo[(size_t)(qbase + l15) * 64 + quad * 8];
    const bf16x8 ql1 = *(const bf16x8*)&khs_lo[(size_t)(qbase + l15) * 64 + 32 + quad * 8];

    bf16x8 ones;
    #pragma unroll
    for (int j = 0; j < 8; ++j) ones[j] = (bf16_t)1.0f;

    f32x4 o0 = {}, o1 = {}, o2 = {}, o3 = {}, o4 = {};

    const unsigned int* mrow = &ShBuf[w * 544 + l15 * 34];      // mrow[t] = word for row l15, tile t
    const bf16_t* kbase = ktile + (size_t)(w * 32) * 2048 + lane * 8;
    const bf16_t* vbase = vtile + (size_t)(w * 32) * 2048 + lane * 8;

    #pragma unroll 4
    for (int t = 0; t < 32; ++t) {
        const unsigned int word = mrow[t];                      // ds_read_b32, no fence
        const bf16_t* kp = kbase + (size_t)t * 2048;
        const bf16_t* vp = vbase + (size_t)t * 2048;

        bf16x8 a00 = *(const bf16x8*)(kp);
        bf16x8 a01 = *(const bf16x8*)(kp + 512);
        bf16x8 a10 = *(const bf16x8*)(kp + 1024);
        bf16x8 a11 = *(const bf16x8*)(kp + 1536);
        bf16x8 bv0 = *(const bf16x8*)(vp);
        bf16x8 bv1 = *(const bf16x8*)(vp + 512);
        bf16x8 bv2 = *(const bf16x8*)(vp + 1024);
        bf16x8 bv3 = *(const bf16x8*)(vp + 1536);

        // S^T tiles: D[m=key-slot][n=query]
        f32x4 zz = {};
        f32x4 c0 = __builtin_amdgcn_mfma_f32_16x16x32_bf16(a00, qh0, zz, 0, 0, 0);
        c0 = __builtin_amdgcn_mfma_f32_16x16x32_bf16(a01, qh1, c0, 0, 0, 0);
        c0 = __builtin_amdgcn_mfma_f32_16x16x32_bf16(a00, ql0, c0, 0, 0, 0);
        c0 = __builtin_amdgcn_mfma_f32_16x16x32_bf16(a01, ql1, c0, 0, 0, 0);
        f32x4 c1 = __builtin_amdgcn_mfma_f32_16x16x32_bf16(a10, qh0, zz, 0, 0, 0);
        c1 = __builtin_amdgcn_mfma_f32_16x16x32_bf16(a11, qh1, c1, 0, 0, 0);
        c1 = __builtin_amdgcn_mfma_f32_16x16x32_bf16(a10, ql0, c1, 0, 0, 0);
        c1 = __builtin_amdgcn_mfma_f32_16x16x32_bf16(a11, ql1, c1, 0, 0, 0);

        // p = maskbit ? exp(s - SMAX) : 0 ; c0[r] -> key 8*quad+r, c1[r] -> +4
        bf16x8 pa;
        #pragma unroll
        for (int r = 0; r < 4; ++r) {
            float p0 = ((word >> (8 * quad + r)) & 1u)
                         ? __builtin_amdgcn_exp2f((c0[r] - SMAX) * L2E) : 0.f;
            float p1 = ((word >> (8 * quad + 4 + r)) & 1u)
                         ? __builtin_amdgcn_exp2f((c1[r] - SMAX) * L2E) : 0.f;
            pa[r]     = (bf16_t)p0;
            pa[4 + r] = (bf16_t)p1;
        }

        // PV + l, all in registers
        o0 = __builtin_amdgcn_mfma_f32_16x16x32_bf16(pa, bv0, o0, 0, 0, 0);
        o1 = __builtin_amdgcn_mfma_f32_16x16x32_bf16(pa, bv1, o1, 0, 0, 0);
        o2 = __builtin_amdgcn_mfma_f32_16x16x32_bf16(pa, bv2, o2, 0, 0, 0);
        o3 = __builtin_amdgcn_mfma_f32_16x16x32_bf16(pa, bv3, o3, 0, 0, 0);
        o4 = __builtin_amdgcn_mfma_f32_16x16x32_bf16(pa, ones, o4, 0, 0, 0);
    }

    // ---- phase 3: 8-wave sum-tree merge (overlaid on ShBuf) ----
    float* M = (float*)ShBuf;
    #pragma unroll
    for (int s = 4; s >= 1; s >>= 1) {
        __syncthreads();
        if (w >= s && w < 2 * s) {
            float* base = M + (w - s) * 16 * 68;
            #pragma unroll
            for (int r = 0; r < 4; ++r) {
                const int row = quad * 4 + r;
                base[row * 68 + l15]      = o0[r];
                base[row * 68 + 16 + l15] = o1[r];
                base[row * 68 + 32 + l15] = o2[r];
                base[row * 68 + 48 + l15] = o3[r];
                if (l15 == 0) base[row * 68 + 64] = o4[r];
            }
        }
        __syncthreads();
        if (w < s) {
            float* base = M + w * 16 * 68;
            #pragma unroll
            for (int r = 0; r < 4; ++r) {
                const int row = quad * 4 + r;
                o0[r] += base[row * 68 + l15];
                o1[r] += base[row * 68 + 16 + l15];
                o2[r] += base[row * 68 + 32 + l15];
                o3[r] += base[row * 68 + 48 + l15];
                o4[r] += base[row * 68 + 64];
            }
        }
    }

    // ---- phase 4: normalize + ELU + direct store (w0 only) ----
    if (w == 0) {
        #pragma unroll
        for (int r = 0; r < 4; ++r) {
            const float l   = o4[r];
            const float inv = l > 0.f ? 1.0f / l : 0.f;
            float v0 = o0[r] * inv, v1 = o1[r] * inv, v2 = o2[r] * inv, v3 = o3[r] * inv;
            v0 = v0 > 0.f ? v0 : expm1f(v0);
            v1 = v1 > 0.f ? v1 : expm1f(v1);
            v2 = v2 > 0.f ? v2 : expm1f(v2);
            v3 = v3 > 0.f ? v3 : expm1f(v3);
            float* op = &out[(size_t)(qbase + quad * 4 + r) * 64 + l15];
            op[0]  = v0;
            op[16] = v1;
            op[32] = v2;
            op[48] = v3;
        }
    }
}

// ---------------------------------------------------------------------------
extern "C" void kernel_launch(void* const* d_in, const int* in_sizes, int n_in,
                              void* d_out, int out_size, void* d_ws, size_t ws_size,
                              hipStream_t stream) {
    const float* input = nullptr;
    const int*   adj   = nullptr;
    const float* kW    = nullptr;
    const float* vW    = nullptr;
    for (int i = 0; i < n_in; ++i) {
        if (in_sizes[i] == 8192 * 512)            input = (const float*)d_in[i];
        else if (in_sizes[i] == 512 * 64) {
            if (!kW) kW = (const float*)d_in[i]; else vW = (const float*)d_in[i];
        } else                                    adj = (const int*)d_in[i];
    }
    float* out = (float*)d_out;

    char* ws = (char*)d_ws;
    bf16_t* khs_hi = (bf16_t*)ws;                            // 1 MB
    bf16_t* khs_lo = (bf16_t*)(ws + 1u * 1024 * 1024);       // 1 MB
    bf16_t* vhT    = (bf16_t*)(ws + 2u * 1024 * 1024);       // 1 MB
    bf16_t* ktile  = (bf16_t*)(ws + 3u * 1024 * 1024);       // 1 MB
    bf16_t* vtile  = (bf16_t*)(ws + 4u * 1024 * 1024);       // 1 MB

    proj_kernel<<<128, 256, 0, stream>>>(input, kW, vW, khs_hi, khs_lo, vhT);
    repack<<<512, 256, 0, stream>>>(khs_hi, vhT, ktile, vtile);
    attn_kernel<<<512, 512, 0, stream>>>(adj, khs_hi, khs_lo, ktile, vtile, out);
}